// Round 2
// baseline (3405.361 us; speedup 1.0000x reference)
//
#include <hip/hip_runtime.h>
#include <hip/hip_bf16.h>

#define NN 50000
#define EE 600000
#define DD 128
#define RR 7
#define SS 8          // R + self-loop slot
#define KK 1024       // SS*DD
#define GG 32
#define BM 128
#define BK 32

typedef float f32x4 __attribute__((ext_vector_type(4)));
typedef short short8 __attribute__((ext_vector_type(8)));

static __device__ __forceinline__ unsigned short f2bf(float f) {
    union { float f; unsigned u; } v; v.f = f;
    unsigned r = v.u + 0x7fff + ((v.u >> 16) & 1);
    return (unsigned short)(r >> 16);
}

// Build W^T (bf16) [128 cols j][1024 k] = concat(lin_w, sl_w) transposed; bias = lin_b+sl_b
__global__ void prep_w(const float* __restrict__ lin_w, const float* __restrict__ sl_w,
                       const float* __restrict__ lin_b, const float* __restrict__ sl_b,
                       unsigned short* __restrict__ Wt, float* __restrict__ bias) {
    int idx = blockIdx.x * 256 + threadIdx.x;   // 0..131071
    if (idx < DD) bias[idx] = lin_b[idx] + sl_b[idx];
    if (idx >= DD * KK) return;
    int j  = idx >> 10;
    int kk = idx & 1023;
    float w = (kk < RR * DD) ? lin_w[kk * DD + j] : sl_w[(kk - RR * DD) * DD + j];
    Wt[(size_t)j * KK + kk] = f2bf(w);
}

// agg[n][slot][d]: zero slots 0..6, slot 7 = h (self-loop operand + residual source)
__global__ void init_agg(const float* __restrict__ h, float* __restrict__ agg) {
    int t = blockIdx.x * 256 + threadIdx.x;     // N*256 float4 slots
    int n = t >> 8, q = t & 255;                // q*4 = column in [0,1024)
    f32x4 v = {0.f, 0.f, 0.f, 0.f};
    if (q >= 224) v = ((const f32x4*)h)[n * 32 + (q - 224)];
    ((f32x4*)agg)[t] = v;
}

__global__ void scatter(const float* __restrict__ h, const int* __restrict__ node_in,
                        const int* __restrict__ node_out, const int* __restrict__ rel,
                        const float* __restrict__ ew, float* __restrict__ agg) {
    int t = blockIdx.x * 256 + threadIdx.x;     // E*32 threads, 4 cols each
    int e = t >> 5, q = t & 31;
    int ni = node_in[e];
    int no = node_out[e];
    int r  = rel[e];
    float w = ew[e];
    f32x4 v = ((const f32x4*)h)[ni * 32 + q];
    float* dst = agg + ((size_t)no * SS + r) * DD + q * 4;
    atomicAdd(dst + 0, v.x * w);
    atomicAdd(dst + 1, v.y * w);
    atomicAdd(dst + 2, v.z * w);
    atomicAdd(dst + 3, v.w * w);
}

// C[n,j] = relu(sum_k A[n,k] W[k,j] + bias[j]) + h_prev[n,j];  A fp32 -> bf16 on stage
__global__ __launch_bounds__(256) void gemm_layer(
        const float* __restrict__ agg, const unsigned short* __restrict__ Wt,
        const float* __restrict__ bias, float* __restrict__ hout) {
    __shared__ short sA[BM * BK];   // [row][k]
    __shared__ short sB[DD * BK];   // [n][k]  (W^T tile)
    int tid = threadIdx.x;
    int wid = tid >> 6, lane = tid & 63;
    int wr = wid >> 1, wc = wid & 1;
    int lm = lane & 15, lg = lane >> 4;
    int bm0 = blockIdx.x * BM;

    f32x4 acc[4][4] = {};
    for (int ks = 0; ks < KK / BK; ++ks) {
        int k0 = ks * BK;
        // stage A: 512 x (8 fp32 -> 8 bf16)
        #pragma unroll
        for (int it = 0; it < 2; ++it) {
            int seg = tid + it * 256;
            int row = seg >> 2, c0 = (seg & 3) * 8;
            int gr = bm0 + row;
            short8 t8 = {};
            if (gr < NN) {
                const f32x4* src = (const f32x4*)(agg + (size_t)gr * KK + k0 + c0);
                f32x4 a0 = src[0], a1 = src[1];
                t8[0] = f2bf(a0.x); t8[1] = f2bf(a0.y); t8[2] = f2bf(a0.z); t8[3] = f2bf(a0.w);
                t8[4] = f2bf(a1.x); t8[5] = f2bf(a1.y); t8[6] = f2bf(a1.z); t8[7] = f2bf(a1.w);
            }
            ((short8*)sA)[seg] = t8;
        }
        // stage B: W^T rows, contiguous 16B chunks
        #pragma unroll
        for (int it = 0; it < 2; ++it) {
            int chunk = tid + it * 256;
            int n = chunk >> 2, c0 = (chunk & 3) * 8;
            ((short8*)sB)[chunk] = *(const short8*)(Wt + (size_t)n * KK + k0 + c0);
        }
        __syncthreads();
        short8 af[4], bfr[4];
        #pragma unroll
        for (int mi = 0; mi < 4; ++mi)
            af[mi] = ((short8*)sA)[(wr * 64 + mi * 16 + lm) * 4 + lg];
        #pragma unroll
        for (int ni = 0; ni < 4; ++ni)
            bfr[ni] = ((short8*)sB)[(wc * 64 + ni * 16 + lm) * 4 + lg];
        #pragma unroll
        for (int mi = 0; mi < 4; ++mi)
            #pragma unroll
            for (int ni = 0; ni < 4; ++ni)
                acc[mi][ni] = __builtin_amdgcn_mfma_f32_16x16x32_bf16(af[mi], bfr[ni], acc[mi][ni], 0, 0, 0);
        __syncthreads();
    }
    // epilogue: D(m,n): m_local = mi*16 + 4*lg + v, n = wc*64 + ni*16 + lm
    #pragma unroll
    for (int mi = 0; mi < 4; ++mi) {
        #pragma unroll
        for (int v = 0; v < 4; ++v) {
            int gm = bm0 + wr * 64 + mi * 16 + lg * 4 + v;
            if (gm >= NN) continue;
            #pragma unroll
            for (int ni = 0; ni < 4; ++ni) {
                int n = wc * 64 + ni * 16 + lm;
                float pre = acc[mi][ni][v] + bias[n];
                float hp  = agg[(size_t)gm * KK + RR * DD + n];   // slot 7 = h_prev
                hout[(size_t)gm * DD + n] = fmaxf(pre, 0.f) + hp;
            }
        }
    }
}

__global__ void zero_gf(float* gf) {
    int t = blockIdx.x * 256 + threadIdx.x;
    if (t < GG * DD) gf[t] = 0.f;
}

// node2graph is sorted: run-length accumulate per thread-column, atomic flush on change.
// 128 threads/block (one per column d), 256 nodes per block.
__global__ __launch_bounds__(128) void readout(const float* __restrict__ h,
                                               const int* __restrict__ n2g,
                                               float* __restrict__ gf) {
    int c0 = blockIdx.x * 256;
    int d = threadIdx.x;                 // 0..127: one column each
    int end = (c0 + 256 < NN) ? c0 + 256 : NN;
    float acc = 0.f;
    int cur = n2g[c0];
    for (int n = c0; n < end; ++n) {
        int g = n2g[n];
        if (g != cur) { atomicAdd(&gf[cur * DD + d], acc); acc = 0.f; cur = g; }
        acc += h[(size_t)n * DD + d];
    }
    atomicAdd(&gf[cur * DD + d], acc);
}

extern "C" void kernel_launch(void* const* d_in, const int* in_sizes, int n_in,
                              void* d_out, int out_size, void* d_ws, size_t ws_size,
                              hipStream_t stream) {
    const float* x      = (const float*)d_in[0];
    const int* node_in  = (const int*)d_in[1];
    const int* node_out = (const int*)d_in[2];
    const int* relation = (const int*)d_in[3];
    const float* ew     = (const float*)d_in[4];
    const int* n2g      = (const int*)d_in[5];
    const float* sl_w[3]  = {(const float*)d_in[8],  (const float*)d_in[12], (const float*)d_in[16]};
    const float* sl_b[3]  = {(const float*)d_in[9],  (const float*)d_in[13], (const float*)d_in[17]};
    const float* lin_w[3] = {(const float*)d_in[10], (const float*)d_in[14], (const float*)d_in[18]};
    const float* lin_b[3] = {(const float*)d_in[11], (const float*)d_in[15], (const float*)d_in[19]};

    float* out = (float*)d_out;
    float* gf = out;                       // [G,D]
    float* nf = out + GG * DD;             // [N,D] node_feature (doubles as h buffer)

    char* ws = (char*)d_ws;
    float* agg = (float*)ws;                                            // N*1024 f32 = 204.8 MB
    float* hA  = (float*)(ws + (size_t)NN * KK * 4);                    // N*128 f32 = 25.6 MB
    unsigned short* Wt = (unsigned short*)(ws + (size_t)NN * KK * 4 + (size_t)NN * DD * 4);
    float* bias = (float*)((char*)Wt + (size_t)3 * KK * DD * 2);

    for (int l = 0; l < 3; ++l)
        prep_w<<<512, 256, 0, stream>>>(lin_w[l], sl_w[l], lin_b[l], sl_b[l],
                                        Wt + (size_t)l * KK * DD, bias + l * DD);

    const float* hcur = x;
    float* houts[3] = { nf, hA, nf };
    for (int l = 0; l < 3; ++l) {
        init_agg<<<NN, 256, 0, stream>>>(hcur, agg);
        scatter<<<(EE * 32) / 256, 256, 0, stream>>>(hcur, node_in, node_out, relation, ew, agg);
        gemm_layer<<<(NN + BM - 1) / BM, 256, 0, stream>>>(agg, Wt + (size_t)l * KK * DD,
                                                           bias + l * DD, houts[l]);
        hcur = houts[l];
    }
    zero_gf<<<(GG * DD + 255) / 256, 256, 0, stream>>>(gf);
    readout<<<(NN + 255) / 128 / 2, 128, 0, stream>>>(nf, n2g, gf);
}

// Round 4
// 513.811 us; speedup vs baseline: 6.6277x; 6.6277x over previous
//
#include <hip/hip_runtime.h>
#include <hip/hip_bf16.h>

#define NN 50000
#define EE 600000
#define DD 128
#define RR 7
#define SS 8            // R + self-loop slot
#define KK 1024         // SS*DD
#define GG 32
#define BM 128
#define BK 32
#define NSEG (NN * RR)  // 350000 CSR segments
#define NB1 ((NSEG + 1023) / 1024)   // 342 scan blocks

typedef float f32x4 __attribute__((ext_vector_type(4)));
typedef short short8 __attribute__((ext_vector_type(8)));
typedef short bf16x4 __attribute__((ext_vector_type(4)));

static __device__ __forceinline__ unsigned short f2bf(float f) {
    union { float f; unsigned u; } v; v.f = f;
    unsigned r = v.u + 0x7fff + ((v.u >> 16) & 1);
    return (unsigned short)(r >> 16);
}

// ---------------- weights prep: W^T bf16 [j][k], bias = lin_b + sl_b ----------------
__global__ void prep_w(const float* __restrict__ lin_w, const float* __restrict__ sl_w,
                       const float* __restrict__ lin_b, const float* __restrict__ sl_b,
                       unsigned short* __restrict__ Wt, float* __restrict__ bias) {
    int idx = blockIdx.x * 256 + threadIdx.x;
    if (idx < DD) bias[idx] = lin_b[idx] + sl_b[idx];
    if (idx >= DD * KK) return;
    int j  = idx >> 10;
    int kk = idx & 1023;
    float w = (kk < RR * DD) ? lin_w[kk * DD + j] : sl_w[(kk - RR * DD) * DD + j];
    Wt[(size_t)j * KK + kk] = f2bf(w);
}

// ---------------- CSR build ----------------
__global__ void zero_ints(int* __restrict__ p, int n) {
    int i = blockIdx.x * 256 + threadIdx.x;
    if (i < n) p[i] = 0;
}

__global__ void hist(const int* __restrict__ node_out, const int* __restrict__ rel,
                     int* __restrict__ counts) {
    int e = blockIdx.x * 256 + threadIdx.x;
    if (e >= EE) return;
    atomicAdd(&counts[node_out[e] * RR + rel[e]], 1);
}

// block-level exclusive scan: 256 threads x 4 elems
__global__ __launch_bounds__(256) void scan1(const int* __restrict__ counts,
                                             int* __restrict__ start, int* __restrict__ bsum) {
    __shared__ int s[256];
    int tid = threadIdx.x;
    int base = blockIdx.x * 1024 + tid * 4;
    int v[4], sum = 0;
    #pragma unroll
    for (int j = 0; j < 4; ++j) {
        v[j] = (base + j < NSEG) ? counts[base + j] : 0;
        sum += v[j];
    }
    s[tid] = sum; __syncthreads();
    for (int off = 1; off < 256; off <<= 1) {
        int t = (tid >= off) ? s[tid - off] : 0;
        __syncthreads();
        s[tid] += t;
        __syncthreads();
    }
    int run = s[tid] - sum;              // exclusive prefix within block
    if (tid == 255) bsum[blockIdx.x] = s[255];
    #pragma unroll
    for (int j = 0; j < 4; ++j) {
        if (base + j < NSEG) { start[base + j] = run; run += v[j]; }
    }
}

__global__ __launch_bounds__(512) void scan2(int* __restrict__ bsum) {
    __shared__ int s[512];
    int tid = threadIdx.x;
    int v = (tid < NB1) ? bsum[tid] : 0;
    s[tid] = v; __syncthreads();
    for (int off = 1; off < 512; off <<= 1) {
        int t = (tid >= off) ? s[tid - off] : 0;
        __syncthreads();
        s[tid] += t;
        __syncthreads();
    }
    if (tid < NB1) bsum[tid] = s[tid] - v;   // exclusive
}

__global__ void scan3(int* __restrict__ start, const int* __restrict__ bsum) {
    int i = blockIdx.x * 256 + threadIdx.x;
    if (i < NSEG) start[i] += bsum[i >> 10];
}

__global__ void fill(const int* __restrict__ node_in, const int* __restrict__ node_out,
                     const int* __restrict__ rel, const float* __restrict__ ew,
                     const int* __restrict__ start, int* __restrict__ cursor,
                     int* __restrict__ e_ni, float* __restrict__ e_w) {
    int e = blockIdx.x * 256 + threadIdx.x;
    if (e >= EE) return;
    int seg = node_out[e] * RR + rel[e];
    int pos = start[seg] + atomicAdd(&cursor[seg], 1);
    e_ni[pos] = node_in[e];
    e_w[pos]  = ew[e];
}

// ---------------- gather aggregation: agg[n][slot][d] bf16, one write per element ----------------
// block = 256 threads = 8 half-wave segment groups; block b covers the 8 slots of node b.
__global__ __launch_bounds__(256) void agg_k(const float* __restrict__ h,
                                             const int* __restrict__ start,
                                             const int* __restrict__ counts,
                                             const int* __restrict__ e_ni,
                                             const float* __restrict__ e_w,
                                             short* __restrict__ aggb) {
    int tid = threadIdx.x;
    int seg = blockIdx.x * 8 + (tid >> 5);   // [0, N*8)
    int no = seg >> 3, r = seg & 7, d4 = tid & 31;
    f32x4 acc = {0.f, 0.f, 0.f, 0.f};
    if (r == 7) {
        acc = ((const f32x4*)h)[no * 32 + d4];
    } else {
        int cs = start[no * RR + r];
        int cn = counts[no * RR + r];
        for (int i = 0; i < cn; ++i) {
            int ni  = e_ni[cs + i];
            float w = e_w[cs + i];
            f32x4 v = ((const f32x4*)h)[ni * 32 + d4];
            acc += v * w;
        }
    }
    bf16x4 o;
    o[0] = (short)f2bf(acc.x); o[1] = (short)f2bf(acc.y);
    o[2] = (short)f2bf(acc.z); o[3] = (short)f2bf(acc.w);
    ((bf16x4*)aggb)[(size_t)seg * 32 + d4] = o;
}

// ---------------- GEMM: C = relu(A W + bias) + h_prev;  A bf16 [N,1024] ----------------
__global__ __launch_bounds__(256) void gemm_layer(
        const short* __restrict__ aggb, const unsigned short* __restrict__ Wt,
        const float* __restrict__ bias, const float* __restrict__ hprev,
        float* __restrict__ hout) {
    __shared__ short sA[BM * BK];
    __shared__ short sB[DD * BK];
    int tid = threadIdx.x;
    int wid = tid >> 6, lane = tid & 63;
    int wr = wid >> 1, wc = wid & 1;
    int lm = lane & 15, lg = lane >> 4;
    int bm0 = blockIdx.x * BM;

    f32x4 acc[4][4] = {};
    for (int ks = 0; ks < KK / BK; ++ks) {
        int k0 = ks * BK;
        #pragma unroll
        for (int it = 0; it < 2; ++it) {
            int seg = tid + it * 256;
            int row = seg >> 2, c0 = (seg & 3) * 8;
            int gr = bm0 + row;
            short8 t8 = {};
            if (gr < NN) t8 = *(const short8*)(aggb + (size_t)gr * KK + k0 + c0);
            ((short8*)sA)[seg] = t8;
        }
        #pragma unroll
        for (int it = 0; it < 2; ++it) {
            int chunk = tid + it * 256;
            int n = chunk >> 2, c0 = (chunk & 3) * 8;
            ((short8*)sB)[chunk] = *(const short8*)(Wt + (size_t)n * KK + k0 + c0);
        }
        __syncthreads();
        short8 af[4], bfr[4];
        #pragma unroll
        for (int mi = 0; mi < 4; ++mi)
            af[mi] = ((short8*)sA)[(wr * 64 + mi * 16 + lm) * 4 + lg];
        #pragma unroll
        for (int ni = 0; ni < 4; ++ni)
            bfr[ni] = ((short8*)sB)[(wc * 64 + ni * 16 + lm) * 4 + lg];
        #pragma unroll
        for (int mi = 0; mi < 4; ++mi)
            #pragma unroll
            for (int ni = 0; ni < 4; ++ni)
                acc[mi][ni] = __builtin_amdgcn_mfma_f32_16x16x32_bf16(af[mi], bfr[ni], acc[mi][ni], 0, 0, 0);
        __syncthreads();
    }
    #pragma unroll
    for (int mi = 0; mi < 4; ++mi) {
        #pragma unroll
        for (int v = 0; v < 4; ++v) {
            int gm = bm0 + wr * 64 + mi * 16 + lg * 4 + v;
            if (gm >= NN) continue;
            #pragma unroll
            for (int ni = 0; ni < 4; ++ni) {
                int n = wc * 64 + ni * 16 + lm;
                float pre = acc[mi][ni][v] + bias[n];
                float hp  = hprev[(size_t)gm * DD + n];
                hout[(size_t)gm * DD + n] = fmaxf(pre, 0.f) + hp;
            }
        }
    }
}

__global__ void zero_gf(float* gf) {
    int t = blockIdx.x * 256 + threadIdx.x;
    if (t < GG * DD) gf[t] = 0.f;
}

// sorted node2graph: run-length accumulate, atomic flush on run change
__global__ __launch_bounds__(128) void readout(const float* __restrict__ h,
                                               const int* __restrict__ n2g,
                                               float* __restrict__ gf) {
    int c0 = blockIdx.x * 256;
    int d = threadIdx.x;
    int end = (c0 + 256 < NN) ? c0 + 256 : NN;
    float acc = 0.f;
    int cur = n2g[c0];
    for (int n = c0; n < end; ++n) {
        int g = n2g[n];
        if (g != cur) { atomicAdd(&gf[cur * DD + d], acc); acc = 0.f; cur = g; }
        acc += h[(size_t)n * DD + d];
    }
    atomicAdd(&gf[cur * DD + d], acc);
}

extern "C" void kernel_launch(void* const* d_in, const int* in_sizes, int n_in,
                              void* d_out, int out_size, void* d_ws, size_t ws_size,
                              hipStream_t stream) {
    const float* x      = (const float*)d_in[0];
    const int* node_in  = (const int*)d_in[1];
    const int* node_out = (const int*)d_in[2];
    const int* relation = (const int*)d_in[3];
    const float* ew     = (const float*)d_in[4];
    const int* n2g      = (const int*)d_in[5];
    const float* sl_w[3]  = {(const float*)d_in[8],  (const float*)d_in[12], (const float*)d_in[16]};
    const float* sl_b[3]  = {(const float*)d_in[9],  (const float*)d_in[13], (const float*)d_in[17]};
    const float* lin_w[3] = {(const float*)d_in[10], (const float*)d_in[14], (const float*)d_in[18]};
    const float* lin_b[3] = {(const float*)d_in[11], (const float*)d_in[15], (const float*)d_in[19]};

    float* out = (float*)d_out;
    float* gf = out;                       // [G,D]
    float* nf = out + GG * DD;             // [N,D] node_feature (doubles as h buffer)

    char* ws = (char*)d_ws;
    size_t off = 0;
    short* aggb = (short*)(ws + off);            off += (size_t)NN * KK * 2;        // 102.4 MB
    float* hA   = (float*)(ws + off);            off += (size_t)NN * DD * 4;        // 25.6 MB
    unsigned short* Wt = (unsigned short*)(ws + off); off += (size_t)3 * KK * DD * 2;
    float* bias = (float*)(ws + off);            off += 3 * DD * 4;
    int* counts = (int*)(ws + off);              off += (size_t)NSEG * 4;
    int* cursor = (int*)(ws + off);              off += (size_t)NSEG * 4;
    int* start  = (int*)(ws + off);              off += (size_t)NSEG * 4;
    int* bsum   = (int*)(ws + off);              off += 512 * 4;
    int* e_ni   = (int*)(ws + off);              off += (size_t)EE * 4;
    float* e_w  = (float*)(ws + off);            off += (size_t)EE * 4;

    for (int l = 0; l < 3; ++l)
        prep_w<<<512, 256, 0, stream>>>(lin_w[l], sl_w[l], lin_b[l], sl_b[l],
                                        Wt + (size_t)l * KK * DD, bias + l * DD);

    // CSR build (edge topology is layer-invariant)
    zero_ints<<<(2 * NSEG + 255) / 256, 256, 0, stream>>>(counts, 2 * NSEG);  // counts+cursor adjacent
    hist<<<(EE + 255) / 256, 256, 0, stream>>>(node_out, relation, counts);
    scan1<<<NB1, 256, 0, stream>>>(counts, start, bsum);
    scan2<<<1, 512, 0, stream>>>(bsum);
    scan3<<<(NSEG + 255) / 256, 256, 0, stream>>>(start, bsum);
    fill<<<(EE + 255) / 256, 256, 0, stream>>>(node_in, node_out, relation, ew,
                                               start, cursor, e_ni, e_w);

    const float* hcur = x;
    float* houts[3] = { nf, hA, nf };
    for (int l = 0; l < 3; ++l) {
        agg_k<<<NN, 256, 0, stream>>>(hcur, start, counts, e_ni, e_w, aggb);
        gemm_layer<<<(NN + BM - 1) / BM, 256, 0, stream>>>(aggb, Wt + (size_t)l * KK * DD,
                                                           bias + l * DD, hcur, houts[l]);
        hcur = houts[l];
    }
    zero_gf<<<(GG * DD + 255) / 256, 256, 0, stream>>>(gf);
    readout<<<(NN + 255) / 256, 128, 0, stream>>>(nf, n2g, gf);
}

// Round 6
// 504.834 us; speedup vs baseline: 6.7455x; 1.0178x over previous
//
#include <hip/hip_runtime.h>
#include <hip/hip_bf16.h>

#define NN 50000
#define EE 600000
#define DD 128
#define RR 7
#define SS 8            // R + self-loop slot
#define KK 1024         // SS*DD
#define GG 32
#define BM 128
#define BK 32
#define NSEG (NN * RR)  // 350000 CSR segments
#define NB1 ((NSEG + 1023) / 1024)   // 342 scan blocks

typedef float f32x4 __attribute__((ext_vector_type(4)));
typedef short short8 __attribute__((ext_vector_type(8)));
typedef unsigned short u16x4 __attribute__((ext_vector_type(4)));

static __device__ __forceinline__ unsigned short f2bf(float f) {
    union { float f; unsigned u; } v; v.f = f;
    unsigned r = v.u + 0x7fff + ((v.u >> 16) & 1);
    return (unsigned short)(r >> 16);
}
static __device__ __forceinline__ float bf2f(unsigned short u) {
    union { unsigned u; float f; } v; v.u = ((unsigned)u) << 16;
    return v.f;
}

// ---------------- weights prep: W^T bf16 [j][k], bias = lin_b + sl_b ----------------
__global__ void prep_w(const float* __restrict__ lin_w, const float* __restrict__ sl_w,
                       const float* __restrict__ lin_b, const float* __restrict__ sl_b,
                       unsigned short* __restrict__ Wt, float* __restrict__ bias) {
    int idx = blockIdx.x * 256 + threadIdx.x;
    if (idx < DD) bias[idx] = lin_b[idx] + sl_b[idx];
    if (idx >= DD * KK) return;
    int j  = idx >> 10;
    int kk = idx & 1023;
    float w = (kk < RR * DD) ? lin_w[kk * DD + j] : sl_w[(kk - RR * DD) * DD + j];
    Wt[(size_t)j * KK + kk] = f2bf(w);
}

// ---------------- CSR build ----------------
__global__ void zero_ints(int* __restrict__ p, int n) {
    int i = blockIdx.x * 256 + threadIdx.x;
    if (i < n) p[i] = 0;
}

__global__ void hist(const int* __restrict__ node_out, const int* __restrict__ rel,
                     int* __restrict__ counts) {
    int e = blockIdx.x * 256 + threadIdx.x;
    if (e >= EE) return;
    atomicAdd(&counts[node_out[e] * RR + rel[e]], 1);
}

// block-level exclusive scan: 256 threads x 4 elems
__global__ __launch_bounds__(256) void scan1(const int* __restrict__ counts,
                                             int* __restrict__ start, int* __restrict__ bsum) {
    __shared__ int s[256];
    int tid = threadIdx.x;
    int base = blockIdx.x * 1024 + tid * 4;
    int v[4], sum = 0;
    #pragma unroll
    for (int j = 0; j < 4; ++j) {
        v[j] = (base + j < NSEG) ? counts[base + j] : 0;
        sum += v[j];
    }
    s[tid] = sum; __syncthreads();
    for (int off = 1; off < 256; off <<= 1) {
        int t = (tid >= off) ? s[tid - off] : 0;
        __syncthreads();
        s[tid] += t;
        __syncthreads();
    }
    int run = s[tid] - sum;
    if (tid == 255) bsum[blockIdx.x] = s[255];
    #pragma unroll
    for (int j = 0; j < 4; ++j) {
        if (base + j < NSEG) { start[base + j] = run; run += v[j]; }
    }
}

__global__ __launch_bounds__(512) void scan2(int* __restrict__ bsum) {
    __shared__ int s[512];
    int tid = threadIdx.x;
    int v = (tid < NB1) ? bsum[tid] : 0;
    s[tid] = v; __syncthreads();
    for (int off = 1; off < 512; off <<= 1) {
        int t = (tid >= off) ? s[tid - off] : 0;
        __syncthreads();
        s[tid] += t;
        __syncthreads();
    }
    if (tid < NB1) bsum[tid] = s[tid] - v;
}

// segd[i] = {global start, count}
__global__ void scan3(const int* __restrict__ start, const int* __restrict__ bsum,
                      const int* __restrict__ counts, int2* __restrict__ segd) {
    int i = blockIdx.x * 256 + threadIdx.x;
    if (i < NSEG) segd[i] = make_int2(start[i] + bsum[i >> 10], counts[i]);
}

__global__ void fill(const int* __restrict__ node_in, const int* __restrict__ node_out,
                     const int* __restrict__ rel, const float* __restrict__ ew,
                     const int2* __restrict__ segd, int* __restrict__ cursor,
                     int2* __restrict__ edges) {
    int e = blockIdx.x * 256 + threadIdx.x;
    if (e >= EE) return;
    int seg = node_out[e] * RR + rel[e];
    int pos = segd[seg].x + atomicAdd(&cursor[seg], 1);
    edges[pos] = make_int2(node_in[e], __float_as_int(ew[e]));
}

// layer-0 bf16 shadow of x, plus aggb slot-7 (self-loop) rows.  EXACTLY NN*32 threads.
__global__ void init_hb(const float* __restrict__ x, unsigned short* __restrict__ hb,
                        unsigned short* __restrict__ aggb) {
    int t = blockIdx.x * 256 + threadIdx.x;     // [0, NN*32)
    if (t >= NN * 32) return;
    int n = t >> 5, q = t & 31;
    f32x4 v = ((const f32x4*)x)[t];
    u16x4 o = { f2bf(v.x), f2bf(v.y), f2bf(v.z), f2bf(v.w) };
    ((u16x4*)hb)[t] = o;
    ((u16x4*)aggb)[((size_t)n * SS + 7) * 32 + q] = o;
}

// ---------------- gather aggregation (bf16 gathers, fp32 accum, bf16 out) ----------------
// 8 segments (32 lanes each) per 256-thread block; NSEG/8 = 43750 blocks exact.
__global__ __launch_bounds__(256) void agg_k(const unsigned short* __restrict__ hb,
                                             const int2* __restrict__ segd,
                                             const int2* __restrict__ edges,
                                             unsigned short* __restrict__ aggb) {
    int tid = threadIdx.x;
    int seg = blockIdx.x * 8 + (tid >> 5);      // [0, NSEG)
    unsigned no = (unsigned)seg / 7u;
    unsigned r  = (unsigned)seg - no * 7u;
    int d4 = tid & 31;
    int2 sd = segd[seg];
    const int2* ep = edges + sd.x;
    f32x4 acc = {0.f, 0.f, 0.f, 0.f};
    for (int i = 0; i < sd.y; ++i) {
        int2 e = ep[i];
        float w = __int_as_float(e.y);
        u16x4 hv = ((const u16x4*)hb)[(size_t)e.x * 32 + d4];
        acc.x += bf2f(hv[0]) * w;
        acc.y += bf2f(hv[1]) * w;
        acc.z += bf2f(hv[2]) * w;
        acc.w += bf2f(hv[3]) * w;
    }
    u16x4 o = { f2bf(acc.x), f2bf(acc.y), f2bf(acc.z), f2bf(acc.w) };
    ((u16x4*)aggb)[((size_t)no * SS + r) * 32 + d4] = o;
}

// ---------------- GEMM: C = relu(A W + bias) + h_prev; epilogue feeds next layer ----------------
__global__ __launch_bounds__(256) void gemm_layer(
        const unsigned short* __restrict__ aggb, const unsigned short* __restrict__ Wt,
        const float* __restrict__ bias, const float* __restrict__ hprev,
        float* __restrict__ hout, unsigned short* __restrict__ hb,
        unsigned short* __restrict__ aggb_w, int write_next) {
    __shared__ short sA[BM * BK];
    __shared__ short sB[DD * BK];
    int tid = threadIdx.x;
    int wid = tid >> 6, lane = tid & 63;
    int wr = wid >> 1, wc = wid & 1;
    int lm = lane & 15, lg = lane >> 4;
    int bm0 = blockIdx.x * BM;

    f32x4 acc[4][4] = {};
    for (int ks = 0; ks < KK / BK; ++ks) {
        int k0 = ks * BK;
        #pragma unroll
        for (int it = 0; it < 2; ++it) {
            int seg = tid + it * 256;
            int row = seg >> 2, c0 = (seg & 3) * 8;
            int gr = bm0 + row;
            short8 t8 = {};
            if (gr < NN) t8 = *(const short8*)(aggb + (size_t)gr * KK + k0 + c0);
            ((short8*)sA)[seg] = t8;
        }
        #pragma unroll
        for (int it = 0; it < 2; ++it) {
            int chunk = tid + it * 256;
            int n = chunk >> 2, c0 = (chunk & 3) * 8;
            ((short8*)sB)[chunk] = *(const short8*)(Wt + (size_t)n * KK + k0 + c0);
        }
        __syncthreads();
        short8 af[4], bfr[4];
        #pragma unroll
        for (int mi = 0; mi < 4; ++mi)
            af[mi] = ((short8*)sA)[(wr * 64 + mi * 16 + lm) * 4 + lg];
        #pragma unroll
        for (int ni = 0; ni < 4; ++ni)
            bfr[ni] = ((short8*)sB)[(wc * 64 + ni * 16 + lm) * 4 + lg];
        #pragma unroll
        for (int mi = 0; mi < 4; ++mi)
            #pragma unroll
            for (int ni = 0; ni < 4; ++ni)
                acc[mi][ni] = __builtin_amdgcn_mfma_f32_16x16x32_bf16(af[mi], bfr[ni], acc[mi][ni], 0, 0, 0);
        __syncthreads();
    }
    #pragma unroll
    for (int mi = 0; mi < 4; ++mi) {
        #pragma unroll
        for (int v = 0; v < 4; ++v) {
            int gm = bm0 + wr * 64 + mi * 16 + lg * 4 + v;
            if (gm >= NN) continue;
            #pragma unroll
            for (int ni = 0; ni < 4; ++ni) {
                int n = wc * 64 + ni * 16 + lm;
                float pre = acc[mi][ni][v] + bias[n];
                float hp  = hprev[(size_t)gm * DD + n];
                float val = fmaxf(pre, 0.f) + hp;
                hout[(size_t)gm * DD + n] = val;
                if (write_next) {
                    unsigned short b = f2bf(val);
                    hb[(size_t)gm * DD + n] = b;                       // gather source
                    aggb_w[((size_t)gm * SS + 7) * DD + n] = b;        // self-loop slot
                }
            }
        }
    }
}

__global__ void zero_gf(float* gf) {
    int t = blockIdx.x * 256 + threadIdx.x;
    if (t < GG * DD) gf[t] = 0.f;
}

// sorted node2graph: run-length accumulate, atomic flush on run change
__global__ __launch_bounds__(128) void readout(const float* __restrict__ h,
                                               const int* __restrict__ n2g,
                                               float* __restrict__ gf) {
    int c0 = blockIdx.x * 256;
    int d = threadIdx.x;
    int end = (c0 + 256 < NN) ? c0 + 256 : NN;
    float acc = 0.f;
    int cur = n2g[c0];
    for (int n = c0; n < end; ++n) {
        int g = n2g[n];
        if (g != cur) { atomicAdd(&gf[cur * DD + d], acc); acc = 0.f; cur = g; }
        acc += h[(size_t)n * DD + d];
    }
    atomicAdd(&gf[cur * DD + d], acc);
}

extern "C" void kernel_launch(void* const* d_in, const int* in_sizes, int n_in,
                              void* d_out, int out_size, void* d_ws, size_t ws_size,
                              hipStream_t stream) {
    const float* x      = (const float*)d_in[0];
    const int* node_in  = (const int*)d_in[1];
    const int* node_out = (const int*)d_in[2];
    const int* relation = (const int*)d_in[3];
    const float* ew     = (const float*)d_in[4];
    const int* n2g      = (const int*)d_in[5];
    const float* sl_w[3]  = {(const float*)d_in[8],  (const float*)d_in[12], (const float*)d_in[16]};
    const float* sl_b[3]  = {(const float*)d_in[9],  (const float*)d_in[13], (const float*)d_in[17]};
    const float* lin_w[3] = {(const float*)d_in[10], (const float*)d_in[14], (const float*)d_in[18]};
    const float* lin_b[3] = {(const float*)d_in[11], (const float*)d_in[15], (const float*)d_in[19]};

    float* out = (float*)d_out;
    float* gf = out;                       // [G,D]
    float* nf = out + GG * DD;             // [N,D] node_feature (doubles as h buffer)

    char* ws = (char*)d_ws;
    size_t off = 0;
    unsigned short* aggb = (unsigned short*)(ws + off); off += (size_t)NN * KK * 2;   // 102.4 MB
    float* hA   = (float*)(ws + off);            off += (size_t)NN * DD * 4;          // 25.6 MB
    unsigned short* hb = (unsigned short*)(ws + off); off += (size_t)NN * DD * 2;     // 12.8 MB
    unsigned short* Wt = (unsigned short*)(ws + off); off += (size_t)3 * KK * DD * 2;
    float* bias = (float*)(ws + off);            off += 3 * DD * 4;
    int* counts = (int*)(ws + off);              off += (size_t)NSEG * 4;
    int* cursor = (int*)(ws + off);              off += (size_t)NSEG * 4;
    int* start  = (int*)(ws + off);              off += (size_t)NSEG * 4;
    int2* segd  = (int2*)(ws + off);             off += (size_t)NSEG * 8;
    int* bsum   = (int*)(ws + off);              off += 512 * 4;
    int2* edges = (int2*)(ws + off);             off += (size_t)EE * 8;

    for (int l = 0; l < 3; ++l)
        prep_w<<<512, 256, 0, stream>>>(lin_w[l], sl_w[l], lin_b[l], sl_b[l],
                                        Wt + (size_t)l * KK * DD, bias + l * DD);

    // CSR build (edge topology is layer-invariant)
    zero_ints<<<(2 * NSEG + 255) / 256, 256, 0, stream>>>(counts, 2 * NSEG);  // counts+cursor adjacent
    hist<<<(EE + 255) / 256, 256, 0, stream>>>(node_out, relation, counts);
    scan1<<<NB1, 256, 0, stream>>>(counts, start, bsum);
    scan2<<<1, 512, 0, stream>>>(bsum);
    scan3<<<(NSEG + 255) / 256, 256, 0, stream>>>(start, bsum, counts, segd);
    fill<<<(EE + 255) / 256, 256, 0, stream>>>(node_in, node_out, relation, ew,
                                               segd, cursor, edges);
    init_hb<<<(NN * 32) / 256, 256, 0, stream>>>(x, hb, aggb);   // 6250 blocks exact

    const float* hcur = x;
    float* houts[3] = { nf, hA, nf };
    for (int l = 0; l < 3; ++l) {
        agg_k<<<NSEG / 8, 256, 0, stream>>>(hb, segd, edges, aggb);
        gemm_layer<<<(NN + BM - 1) / BM, 256, 0, stream>>>(aggb, Wt + (size_t)l * KK * DD,
                                                           bias + l * DD, hcur, houts[l],
                                                           hb, aggb, l < 2 ? 1 : 0);
        hcur = houts[l];
    }
    zero_gf<<<(GG * DD + 255) / 256, 256, 0, stream>>>(gf);
    readout<<<(NN + 255) / 256, 128, 0, stream>>>(nf, n2g, gf);
}

// Round 7
// 488.643 us; speedup vs baseline: 6.9690x; 1.0331x over previous
//
#include <hip/hip_runtime.h>
#include <hip/hip_bf16.h>

#define NN 50000
#define EE 600000
#define DD 128
#define RR 7
#define SS 8            // R + self-loop slot
#define KK 1024         // SS*DD
#define GG 32
#define BM 128
#define BK 32
#define NSEG (NN * RR)  // 350000 CSR segments
#define NB1 ((NSEG + 1023) / 1024)   // 342 scan blocks

typedef float f32x4 __attribute__((ext_vector_type(4)));
typedef short short8 __attribute__((ext_vector_type(8)));
typedef unsigned short u16x4 __attribute__((ext_vector_type(4)));

static __device__ __forceinline__ unsigned short f2bf(float f) {
    union { float f; unsigned u; } v; v.f = f;
    unsigned r = v.u + 0x7fff + ((v.u >> 16) & 1);
    return (unsigned short)(r >> 16);
}
static __device__ __forceinline__ float bf2f(unsigned short u) {
    union { unsigned u; float f; } v; v.u = ((unsigned)u) << 16;
    return v.f;
}

// ---------------- weights prep: W^T bf16 [j][k], bias = lin_b + sl_b ----------------
__global__ void prep_w(const float* __restrict__ lin_w, const float* __restrict__ sl_w,
                       const float* __restrict__ lin_b, const float* __restrict__ sl_b,
                       unsigned short* __restrict__ Wt, float* __restrict__ bias) {
    int idx = blockIdx.x * 256 + threadIdx.x;
    if (idx < DD) bias[idx] = lin_b[idx] + sl_b[idx];
    if (idx >= DD * KK) return;
    int j  = idx >> 10;
    int kk = idx & 1023;
    float w = (kk < RR * DD) ? lin_w[kk * DD + j] : sl_w[(kk - RR * DD) * DD + j];
    Wt[(size_t)j * KK + kk] = f2bf(w);
}

// ---------------- CSR build ----------------
__global__ void zero_ints(int* __restrict__ p, int n) {
    int i = blockIdx.x * 256 + threadIdx.x;
    if (i < n) p[i] = 0;
}

__global__ void hist(const int* __restrict__ node_out, const int* __restrict__ rel,
                     int* __restrict__ counts) {
    int e = blockIdx.x * 256 + threadIdx.x;
    if (e >= EE) return;
    atomicAdd(&counts[node_out[e] * RR + rel[e]], 1);
}

// block-level exclusive scan: 256 threads x 4 elems
__global__ __launch_bounds__(256) void scan1(const int* __restrict__ counts,
                                             int* __restrict__ start, int* __restrict__ bsum) {
    __shared__ int s[256];
    int tid = threadIdx.x;
    int base = blockIdx.x * 1024 + tid * 4;
    int v[4], sum = 0;
    #pragma unroll
    for (int j = 0; j < 4; ++j) {
        v[j] = (base + j < NSEG) ? counts[base + j] : 0;
        sum += v[j];
    }
    s[tid] = sum; __syncthreads();
    for (int off = 1; off < 256; off <<= 1) {
        int t = (tid >= off) ? s[tid - off] : 0;
        __syncthreads();
        s[tid] += t;
        __syncthreads();
    }
    int run = s[tid] - sum;
    if (tid == 255) bsum[blockIdx.x] = s[255];
    #pragma unroll
    for (int j = 0; j < 4; ++j) {
        if (base + j < NSEG) { start[base + j] = run; run += v[j]; }
    }
}

__global__ __launch_bounds__(512) void scan2(int* __restrict__ bsum) {
    __shared__ int s[512];
    int tid = threadIdx.x;
    int v = (tid < NB1) ? bsum[tid] : 0;
    s[tid] = v; __syncthreads();
    for (int off = 1; off < 512; off <<= 1) {
        int t = (tid >= off) ? s[tid - off] : 0;
        __syncthreads();
        s[tid] += t;
        __syncthreads();
    }
    if (tid < NB1) bsum[tid] = s[tid] - v;
}

// segd[i] = {global start, count}
__global__ void scan3(const int* __restrict__ start, const int* __restrict__ bsum,
                      const int* __restrict__ counts, int2* __restrict__ segd) {
    int i = blockIdx.x * 256 + threadIdx.x;
    if (i < NSEG) segd[i] = make_int2(start[i] + bsum[i >> 10], counts[i]);
}

__global__ void fill(const int* __restrict__ node_in, const int* __restrict__ node_out,
                     const int* __restrict__ rel, const float* __restrict__ ew,
                     const int2* __restrict__ segd, int* __restrict__ cursor,
                     int2* __restrict__ edges) {
    int e = blockIdx.x * 256 + threadIdx.x;
    if (e >= EE) return;
    int seg = node_out[e] * RR + rel[e];
    int pos = segd[seg].x + atomicAdd(&cursor[seg], 1);
    edges[pos] = make_int2(node_in[e], __float_as_int(ew[e]));
}

// layer-0 bf16 shadow of x, plus aggb slot-7 (self-loop) rows.  EXACTLY NN*32 threads.
__global__ void init_hb(const float* __restrict__ x, unsigned short* __restrict__ hb,
                        unsigned short* __restrict__ aggb) {
    int t = blockIdx.x * 256 + threadIdx.x;     // [0, NN*32)
    if (t >= NN * 32) return;
    int n = t >> 5, q = t & 31;
    f32x4 v = ((const f32x4*)x)[t];
    u16x4 o = { f2bf(v.x), f2bf(v.y), f2bf(v.z), f2bf(v.w) };
    ((u16x4*)hb)[t] = o;
    ((u16x4*)aggb)[((size_t)n * SS + 7) * 32 + q] = o;
}

// ---------------- gather aggregation (bf16 gathers, fp32 accum, bf16 out) ----------------
// 8 segments (32 lanes each) per 256-thread block; NSEG/8 = 43750 blocks exact.
__global__ __launch_bounds__(256) void agg_k(const unsigned short* __restrict__ hb,
                                             const int2* __restrict__ segd,
                                             const int2* __restrict__ edges,
                                             unsigned short* __restrict__ aggb) {
    int tid = threadIdx.x;
    int seg = blockIdx.x * 8 + (tid >> 5);      // [0, NSEG)
    unsigned no = (unsigned)seg / 7u;
    unsigned r  = (unsigned)seg - no * 7u;
    int d4 = tid & 31;
    int2 sd = segd[seg];
    const int2* ep = edges + sd.x;
    f32x4 acc = {0.f, 0.f, 0.f, 0.f};
    int cnt = sd.y;
    if (cnt > 0) {
        int2 e = ep[0];
        for (int i = 0; i < cnt; ++i) {
            int2 en = (i + 1 < cnt) ? ep[i + 1] : e;   // prefetch next record
            float w = __int_as_float(e.y);
            u16x4 hv = ((const u16x4*)hb)[(size_t)e.x * 32 + d4];
            acc.x += bf2f(hv[0]) * w;
            acc.y += bf2f(hv[1]) * w;
            acc.z += bf2f(hv[2]) * w;
            acc.w += bf2f(hv[3]) * w;
            e = en;
        }
    }
    u16x4 o = { f2bf(acc.x), f2bf(acc.y), f2bf(acc.z), f2bf(acc.w) };
    ((u16x4*)aggb)[((size_t)no * SS + r) * 32 + d4] = o;
}

// ---------------- GEMM: C = relu(A W + bias) + h_prev; epilogue feeds next layer ----------------
__global__ __launch_bounds__(256) void gemm_layer(
        const unsigned short* __restrict__ aggb, const unsigned short* __restrict__ Wt,
        const float* __restrict__ bias, const float* __restrict__ hprev,
        float* __restrict__ hout, unsigned short* __restrict__ hb,
        unsigned short* __restrict__ aggb_w, int write_next) {
    __shared__ short sA[BM * BK];
    __shared__ short sB[DD * BK];
    int tid = threadIdx.x;
    int wid = tid >> 6, lane = tid & 63;
    int wr = wid >> 1, wc = wid & 1;
    int lm = lane & 15, lg = lane >> 4;
    int bm0 = blockIdx.x * BM;

    f32x4 acc[4][4] = {};
    for (int ks = 0; ks < KK / BK; ++ks) {
        int k0 = ks * BK;
        #pragma unroll
        for (int it = 0; it < 2; ++it) {
            int seg = tid + it * 256;
            int row = seg >> 2, c0 = (seg & 3) * 8;
            int gr = bm0 + row;
            short8 t8 = {};
            if (gr < NN) t8 = *(const short8*)(aggb + (size_t)gr * KK + k0 + c0);
            ((short8*)sA)[seg] = t8;
        }
        #pragma unroll
        for (int it = 0; it < 2; ++it) {
            int chunk = tid + it * 256;
            int n = chunk >> 2, c0 = (chunk & 3) * 8;
            ((short8*)sB)[chunk] = *(const short8*)(Wt + (size_t)n * KK + k0 + c0);
        }
        __syncthreads();
        short8 af[4], bfr[4];
        #pragma unroll
        for (int mi = 0; mi < 4; ++mi)
            af[mi] = ((short8*)sA)[(wr * 64 + mi * 16 + lm) * 4 + lg];
        #pragma unroll
        for (int ni = 0; ni < 4; ++ni)
            bfr[ni] = ((short8*)sB)[(wc * 64 + ni * 16 + lm) * 4 + lg];
        #pragma unroll
        for (int mi = 0; mi < 4; ++mi)
            #pragma unroll
            for (int ni = 0; ni < 4; ++ni)
                acc[mi][ni] = __builtin_amdgcn_mfma_f32_16x16x32_bf16(af[mi], bfr[ni], acc[mi][ni], 0, 0, 0);
        __syncthreads();
    }
    #pragma unroll
    for (int mi = 0; mi < 4; ++mi) {
        #pragma unroll
        for (int v = 0; v < 4; ++v) {
            int gm = bm0 + wr * 64 + mi * 16 + lg * 4 + v;
            if (gm >= NN) continue;
            #pragma unroll
            for (int ni = 0; ni < 4; ++ni) {
                int n = wc * 64 + ni * 16 + lm;
                float pre = acc[mi][ni][v] + bias[n];
                float hp  = hprev[(size_t)gm * DD + n];
                float val = fmaxf(pre, 0.f) + hp;
                hout[(size_t)gm * DD + n] = val;
                if (write_next) {
                    unsigned short b = f2bf(val);
                    hb[(size_t)gm * DD + n] = b;                       // gather source
                    aggb_w[((size_t)gm * SS + 7) * DD + n] = b;        // self-loop slot
                }
            }
        }
    }
}

__global__ void zero_gf(float* gf) {
    int t = blockIdx.x * 256 + threadIdx.x;
    if (t < GG * DD) gf[t] = 0.f;
}

// Parallel readout: block = 128 nodes, 8 row-streams x 32 lanes (f32x4 cols).
// Per-stream rows are sorted (global sort) -> run-length accumulate + atomic flush.
__global__ __launch_bounds__(256) void readout(const float* __restrict__ h,
                                               const int* __restrict__ n2g,
                                               float* __restrict__ gf) {
    int c0 = blockIdx.x * 128;
    int rg = threadIdx.x >> 5, d4 = threadIdx.x & 31;
    f32x4 acc = {0.f, 0.f, 0.f, 0.f};
    int cur = -1;
    #pragma unroll 4
    for (int it = 0; it < 16; ++it) {
        int row = c0 + it * 8 + rg;
        if (row >= NN) break;
        int g = n2g[row];
        if (g != cur) {
            if (cur >= 0) {
                atomicAdd(&gf[cur * DD + d4 * 4 + 0], acc.x);
                atomicAdd(&gf[cur * DD + d4 * 4 + 1], acc.y);
                atomicAdd(&gf[cur * DD + d4 * 4 + 2], acc.z);
                atomicAdd(&gf[cur * DD + d4 * 4 + 3], acc.w);
            }
            cur = g;
            acc = (f32x4){0.f, 0.f, 0.f, 0.f};
        }
        acc += ((const f32x4*)h)[(size_t)row * 32 + d4];
    }
    if (cur >= 0) {
        atomicAdd(&gf[cur * DD + d4 * 4 + 0], acc.x);
        atomicAdd(&gf[cur * DD + d4 * 4 + 1], acc.y);
        atomicAdd(&gf[cur * DD + d4 * 4 + 2], acc.z);
        atomicAdd(&gf[cur * DD + d4 * 4 + 3], acc.w);
    }
}

extern "C" void kernel_launch(void* const* d_in, const int* in_sizes, int n_in,
                              void* d_out, int out_size, void* d_ws, size_t ws_size,
                              hipStream_t stream) {
    const float* x      = (const float*)d_in[0];
    const int* node_in  = (const int*)d_in[1];
    const int* node_out = (const int*)d_in[2];
    const int* relation = (const int*)d_in[3];
    const float* ew     = (const float*)d_in[4];
    const int* n2g      = (const int*)d_in[5];
    const float* sl_w[3]  = {(const float*)d_in[8],  (const float*)d_in[12], (const float*)d_in[16]};
    const float* sl_b[3]  = {(const float*)d_in[9],  (const float*)d_in[13], (const float*)d_in[17]};
    const float* lin_w[3] = {(const float*)d_in[10], (const float*)d_in[14], (const float*)d_in[18]};
    const float* lin_b[3] = {(const float*)d_in[11], (const float*)d_in[15], (const float*)d_in[19]};

    float* out = (float*)d_out;
    float* gf = out;                       // [G,D]
    float* nf = out + GG * DD;             // [N,D] node_feature (doubles as h buffer)

    char* ws = (char*)d_ws;
    size_t off = 0;
    unsigned short* aggb = (unsigned short*)(ws + off); off += (size_t)NN * KK * 2;   // 102.4 MB
    float* hA   = (float*)(ws + off);            off += (size_t)NN * DD * 4;          // 25.6 MB
    unsigned short* hb = (unsigned short*)(ws + off); off += (size_t)NN * DD * 2;     // 12.8 MB
    unsigned short* Wt = (unsigned short*)(ws + off); off += (size_t)3 * KK * DD * 2;
    float* bias = (float*)(ws + off);            off += 3 * DD * 4;
    int* counts = (int*)(ws + off);              off += (size_t)NSEG * 4;
    int* cursor = (int*)(ws + off);              off += (size_t)NSEG * 4;
    int* start  = (int*)(ws + off);              off += (size_t)NSEG * 4;
    int2* segd  = (int2*)(ws + off);             off += (size_t)NSEG * 8;
    int* bsum   = (int*)(ws + off);              off += 512 * 4;
    int2* edges = (int2*)(ws + off);             off += (size_t)EE * 8;

    for (int l = 0; l < 3; ++l)
        prep_w<<<512, 256, 0, stream>>>(lin_w[l], sl_w[l], lin_b[l], sl_b[l],
                                        Wt + (size_t)l * KK * DD, bias + l * DD);

    // CSR build (edge topology is layer-invariant)
    zero_ints<<<(2 * NSEG + 255) / 256, 256, 0, stream>>>(counts, 2 * NSEG);  // counts+cursor adjacent
    hist<<<(EE + 255) / 256, 256, 0, stream>>>(node_out, relation, counts);
    scan1<<<NB1, 256, 0, stream>>>(counts, start, bsum);
    scan2<<<1, 512, 0, stream>>>(bsum);
    scan3<<<(NSEG + 255) / 256, 256, 0, stream>>>(start, bsum, counts, segd);
    fill<<<(EE + 255) / 256, 256, 0, stream>>>(node_in, node_out, relation, ew,
                                               segd, cursor, edges);
    init_hb<<<(NN * 32) / 256, 256, 0, stream>>>(x, hb, aggb);   // 6250 blocks exact

    const float* hcur = x;
    float* houts[3] = { nf, hA, nf };
    for (int l = 0; l < 3; ++l) {
        agg_k<<<NSEG / 8, 256, 0, stream>>>(hb, segd, edges, aggb);
        gemm_layer<<<(NN + BM - 1) / BM, 256, 0, stream>>>(aggb, Wt + (size_t)l * KK * DD,
                                                           bias + l * DD, hcur, houts[l],
                                                           hb, aggb, l < 2 ? 1 : 0);
        hcur = houts[l];
    }
    zero_gf<<<(GG * DD + 255) / 256, 256, 0, stream>>>(gf);
    readout<<<(NN + 127) / 128, 256, 0, stream>>>(nf, n2g, gf);
}